// Round 14
// baseline (636.854 us; speedup 1.0000x reference)
//
#include <hip/hip_runtime.h>
#include <cstdint>
#include <cstddef>

#define DIMD 1024
#define SEQ  4096
#define BATCH 4
#define MTOT (BATCH*SEQ)   // 16384 rows
#define NCHUNK 64          // scan chunks
#define CLEN   64          // chunk length

typedef __attribute__((ext_vector_type(8))) short short8;
typedef __attribute__((ext_vector_type(4))) float floatx4;

__device__ __forceinline__ unsigned short f2bf(float f){
  unsigned u = __float_as_uint(f);
  u += 0x7fffu + ((u >> 16) & 1u);   // RNE
  return (unsigned short)(u >> 16);
}
__device__ __forceinline__ float bf2f(unsigned short u){
  return __uint_as_float((unsigned)u << 16);
}

// hardware-pipe transcendentals (v_exp_f32 is 2^x; v_rcp_f32): ~5 insts vs ~25-45 for libm
__device__ __forceinline__ float fast_sigmoid(float x){
  return __builtin_amdgcn_rcpf(1.f + __builtin_amdgcn_exp2f(-1.442695041f * x));
}
__device__ __forceinline__ float fast_gelu(float x){
  float u = 1.595769122f * x * (1.f + 0.044715f * x * x);
  return x * fast_sigmoid(u);
}

__device__ __forceinline__ void async16(const void* g, void* l){
  __builtin_amdgcn_global_load_lds(
      (const __attribute__((address_space(1))) void*)g,
      (__attribute__((address_space(3))) void*)l, 16, 0, 0);
}

// ---------------- weight fp32 -> bf16 ----------------
__global__ void f32_to_bf16_kernel(const float* __restrict__ in,
                                   unsigned short* __restrict__ out, int n){
  int i = (blockIdx.x * 256 + threadIdx.x) * 4;
  if (i < n){
    float4 v = *(const float4*)(in + i);
    uint2 o;
    o.x = (unsigned)f2bf(v.x) | ((unsigned)f2bf(v.y) << 16);
    o.y = (unsigned)f2bf(v.z) | ((unsigned)f2bf(v.w) << 16);
    *(uint2*)(out + i) = o;
  }
}

// ---------------- LayerNorm (fp32 in -> bf16 out) ----------------
__global__ __launch_bounds__(256)
void ln_kernel(const float* __restrict__ X, const float* __restrict__ w,
               const float* __restrict__ b, unsigned short* __restrict__ H){
  const int row = blockIdx.x;
  const int tid = threadIdx.x;
  const float4 xv = ((const float4*)(X + (size_t)row * DIMD))[tid];
  float s  = xv.x + xv.y + xv.z + xv.w;
  float ss = xv.x*xv.x + xv.y*xv.y + xv.z*xv.z + xv.w*xv.w;
  #pragma unroll
  for (int o = 32; o; o >>= 1){
    s  += __shfl_down(s, o);
    ss += __shfl_down(ss, o);
  }
  __shared__ float ps[4], pss[4], mv[2];
  const int wid = tid >> 6, lane = tid & 63;
  if (lane == 0){ ps[wid] = s; pss[wid] = ss; }
  __syncthreads();
  if (tid == 0){
    float S1 = ps[0]+ps[1]+ps[2]+ps[3];
    float S2 = pss[0]+pss[1]+pss[2]+pss[3];
    float m = S1 * (1.0f / DIMD);
    float var = S2 * (1.0f / DIMD) - m*m;
    mv[0] = m; mv[1] = rsqrtf(var + 1e-5f);
  }
  __syncthreads();
  const float m = mv[0], rs = mv[1];
  const float4 wv = ((const float4*)w)[tid];
  const float4 bv = ((const float4*)b)[tid];
  float o0 = (xv.x - m) * rs * wv.x + bv.x;
  float o1 = (xv.y - m) * rs * wv.y + bv.y;
  float o2 = (xv.z - m) * rs * wv.z + bv.z;
  float o3 = (xv.w - m) * rs * wv.w + bv.w;
  uint2 o;
  o.x = (unsigned)f2bf(o0) | ((unsigned)f2bf(o1) << 16);
  o.y = (unsigned)f2bf(o2) | ((unsigned)f2bf(o3) << 16);
  ((uint2*)(H + (size_t)row * DIMD))[tid] = o;
}

// ------- m97-replica: 128x128 4-wave GEMM, BK=32, 2-phase dbuf, compiler-scheduled -------
// C[M,N(ldc)] = A[M,K(lda)] @ Bw[N,K(ldb)]^T. 256 thr = 4 waves (2x2), per-wave 64x64.
// stage(t+1) BEFORE compute(t); ONE __syncthreads per K-step (compiler emits the waits —
// the proven 874-912 TF structure). All prior wounds removed: no launch-bounds VGPR cap,
// 0-conflict swizzle (16B slot' = rq ^ ((row>>1)&3), inverse-applied on DMA global source),
// hw-transcendental epilogue, slab-repacked bf16 stores. LDS 48KB -> 3 blocks/CU.
// EPI: 2 gelu->bf16, 3 acc+bias+out[o]->f32, 4 acc+out[o]->f32,
//      5 stacked gate/val: col<1024 -> sigmoid->Out, else plain->Out2 (both ld 1024)
template<int EPI>
__global__ __launch_bounds__(256)
void gemm128(const unsigned short* __restrict__ A, int lda,
             const unsigned short* __restrict__ Bw, int ldb,
             const float* __restrict__ bias, const float* __restrict__ bias2,
             void* __restrict__ OutP, void* __restrict__ Out2P,
             int ldc, int grid_n, int K)
{
  __shared__ unsigned short Alds[2][128*32];   // 8KB per buf, 64B rows
  __shared__ unsigned short Blds[2][128*32];
  __shared__ char slab[4][4096];               // bf16 epilogue repack (total 48KB)
  const int tid = threadIdx.x;
  // T1: XCD-aware bijective swizzle (grid % 8 == 0 by construction)
  const int bid = ((int)blockIdx.x & 7) * ((int)gridDim.x >> 3) + ((int)blockIdx.x >> 3);
  const int bm = bid / grid_n, bn = bid % grid_n;
  const int row0 = bm * 128, col0 = bn * 128;
  const int wid = tid >> 6, lane = tid & 63;
  const int wr = wid >> 1, wc = wid & 1;
  const int l15 = lane & 15, rq = lane >> 4;

  // staging: issue i covers rows [i*64,(i+1)*64); thread row = tid>>2, dest 16B-slot = tid&3
  // source k-slot = (tid&3) ^ sw(row), sw(r)=(r>>1)&3 = (tid>>3)&3  (row+64 has same sw)
  const int st_sl = (tid & 3) ^ ((tid >> 3) & 3);
  const unsigned short* aP = A  + (size_t)(row0 + (tid >> 2)) * lda + st_sl * 8;
  const unsigned short* bP = Bw + (size_t)(col0 + (tid >> 2)) * ldb + st_sl * 8;
  const int st_off = tid * 16;
  const size_t lda64 = (size_t)lda * 64, ldb64 = (size_t)ldb * 64;

  // read offsets (loop-invariant): byte = r*64 + ((rq ^ ((r>>1)&3))<<4)
  int offA[4], offB[4];
  #pragma unroll
  for (int m = 0; m < 4; ++m){
    const int r = wr*64 + m*16 + l15;
    offA[m] = r*64 + ((rq ^ ((r >> 1) & 3)) << 4);
  }
  #pragma unroll
  for (int n = 0; n < 4; ++n){
    const int r = wc*64 + n*16 + l15;
    offB[n] = r*64 + ((rq ^ ((r >> 1) & 3)) << 4);
  }

  floatx4 acc[4][4];
  #pragma unroll
  for (int m = 0; m < 4; ++m)
    #pragma unroll
    for (int n = 0; n < 4; ++n)
      acc[m][n] = (floatx4){0.f, 0.f, 0.f, 0.f};

  auto stage = [&](int b, int kel){
    async16(aP + kel,         (char*)(&Alds[b][0]) + st_off);
    async16(aP + lda64 + kel, (char*)(&Alds[b][0]) + 4096 + st_off);
    async16(bP + kel,         (char*)(&Blds[b][0]) + st_off);
    async16(bP + ldb64 + kel, (char*)(&Blds[b][0]) + 4096 + st_off);
  };
  auto compute = [&](int b){
    short8 af[4], bfr[4];
    #pragma unroll
    for (int m = 0; m < 4; ++m)
      af[m] = *(const short8*)((const char*)(&Alds[b][0]) + offA[m]);
    #pragma unroll
    for (int n = 0; n < 4; ++n)
      bfr[n] = *(const short8*)((const char*)(&Blds[b][0]) + offB[n]);
    #pragma unroll
    for (int m = 0; m < 4; ++m)
      #pragma unroll
      for (int n = 0; n < 4; ++n)
        acc[m][n] = __builtin_amdgcn_mfma_f32_16x16x32_bf16(af[m], bfr[n], acc[m][n], 0, 0, 0);
  };

  const int nt = K >> 5;
  stage(0, 0);
  __syncthreads();                    // compiler-emitted vmcnt drain: buf0 ready
  int cur = 0;
  for (int t = 0; t < nt - 1; ++t){
    stage(cur ^ 1, (t + 1) << 5);     // issue next tile BEFORE compute
    compute(cur);                     // load latency hides under ds_read+MFMA
    __syncthreads();
    cur ^= 1;
  }
  compute(cur);

  if constexpr (EPI == 2 || EPI == 5){
    // LDS-repack epilogue: wave-private slab -> 128B-coalesced dwordx4 stores
    char* sl = &slab[wid][0];
    unsigned short* dst; int colw; int ldout; bool sigm = false;
    const float* bsel;
    if constexpr (EPI == 5){
      const int c0 = col0 + wc * 64;
      if (c0 < 1024){ dst = (unsigned short*)OutP;  colw = c0;        bsel = bias;  sigm = true;  }
      else          { dst = (unsigned short*)Out2P; colw = c0 - 1024; bsel = bias2; sigm = false; }
      ldout = 1024;
    } else {
      dst = (unsigned short*)OutP; colw = col0 + wc * 64; bsel = bias; ldout = ldc;
    }
    const int rdrow = lane >> 3;
    const int rdoff  = rdrow * 128 + (((lane & 7) ^ (rdrow & 7)) << 4);
    const int rdoff2 = (rdrow + 8) * 128 + (((lane & 7) ^ ((rdrow + 8) & 7)) << 4);
    const int rdsl = (lane & 7) * 16;
    #pragma unroll
    for (int m = 0; m < 4; ++m){
      #pragma unroll
      for (int n = 0; n < 4; ++n){
        const float bs = bsel[colw + n*16 + l15];
        const int cchunk = n*2 + (l15 >> 3);
        #pragma unroll
        for (int j = 0; j < 4; ++j){
          const float val = acc[m][n][j] + bs;
          float r;
          if constexpr (EPI == 2){
            r = fast_gelu(val);
          } else {
            r = sigm ? fast_sigmoid(val) : val;
          }
          const int rr = rq*4 + j;
          *(unsigned short*)(sl + rr*128 + ((cchunk ^ (rr & 7)) << 4) + (l15 & 7)*2) = f2bf(r);
        }
      }
      asm volatile("s_waitcnt lgkmcnt(0)" ::: "memory");   // slab writes landed (wave-local)
      uint4 w0 = *(const uint4*)(sl + rdoff);
      uint4 w1 = *(const uint4*)(sl + rdoff2);
      asm volatile("s_waitcnt lgkmcnt(0)" ::: "memory");   // reads done before next m overwrites
      const int growb = row0 + wr * 64 + m * 16;
      *(uint4*)((char*)(dst + (size_t)(growb + rdrow) * ldout + colw) + rdsl) = w0;
      *(uint4*)((char*)(dst + (size_t)(growb + rdrow + 8) * ldout + colw) + rdsl) = w1;
    }
  } else {
    // f32 RMW epilogue (64B segments per 16-lane group)
    #pragma unroll
    for (int n = 0; n < 4; ++n){
      const int col = col0 + wc * 64 + n * 16 + l15;
      const float bs = (EPI == 4) ? 0.f : bias[col];
      #pragma unroll
      for (int m = 0; m < 4; ++m){
        const int rowb = row0 + wr * 64 + m * 16 + rq * 4;
        #pragma unroll
        for (int j = 0; j < 4; ++j){
          const size_t o = (size_t)(rowb + j) * ldc + col;
          float* O = (float*)OutP;
          O[o] = acc[m][n][j] + bs + O[o];
        }
      }
    }
  }
}

// ---------------- 3-phase chunked scan over sequence (bf16 G/V) ----------------
__global__ __launch_bounds__(256)
void scan_sums(const unsigned short* __restrict__ G, const unsigned short* __restrict__ V,
               float* __restrict__ SG, float* __restrict__ SGV){
  const int bc = blockIdx.x;                 // b*NCHUNK + c
  const int d  = blockIdx.y * 256 + threadIdx.x;
  const int b = bc >> 6, c = bc & 63;
  size_t base = ((size_t)b * SEQ + (size_t)c * CLEN) * DIMD + d;
  float sg = 0.f, sgv = 0.f;
  for (int i = 0; i < CLEN; ++i){
    float g = bf2f(G[base + (size_t)i * DIMD]);
    float v = bf2f(V[base + (size_t)i * DIMD]);
    sg += g; sgv += g * v;
  }
  SG[(size_t)bc * DIMD + d] = sg;
  SGV[(size_t)bc * DIMD + d] = sgv;
}

__global__ __launch_bounds__(256)
void scan_prefix(float* __restrict__ SG, float* __restrict__ SGV){
  const int b = blockIdx.x;
  const int d = blockIdx.y * 256 + threadIdx.x;
  float rg = 0.f, rgv = 0.f;
  for (int c = 0; c < NCHUNK; ++c){
    size_t i = ((size_t)(b * NCHUNK + c)) * DIMD + d;
    float tg = SG[i], tv = SGV[i];
    SG[i] = rg; SGV[i] = rgv;
    rg += tg; rgv += tv;
  }
}

__global__ __launch_bounds__(256)
void scan_final(const unsigned short* __restrict__ G, const unsigned short* __restrict__ V,
                const float* __restrict__ SG, const float* __restrict__ SGV,
                const float* __restrict__ X, float* __restrict__ X2){
  const int bc = blockIdx.x;
  const int d  = blockIdx.y * 256 + threadIdx.x;
  const int b = bc >> 6, c = bc & 63;
  size_t base = ((size_t)b * SEQ + (size_t)c * CLEN) * DIMD + d;
  float rg  = SG[(size_t)bc * DIMD + d];
  float rgv = SGV[(size_t)bc * DIMD + d];
  for (int i = 0; i < CLEN; ++i){
    size_t idx = base + (size_t)i * DIMD;
    float g = bf2f(G[idx]), v = bf2f(V[idx]);
    rg += g; rgv += g * v;
    int s = c * CLEN + i;
    float pf = (float)(s + 1) * (1.0f / SEQ) + 0.1f;
    float mem = rgv * rsqrtf((rg + 1e-6f) * pf);
    X2[idx] = X[idx] + mem;
  }
}

extern "C" void kernel_launch(void* const* d_in, const int* in_sizes, int n_in,
                              void* d_out, int out_size, void* d_ws, size_t ws_size,
                              hipStream_t stream)
{
  const float* x     = (const float*)d_in[0];
  const float* ln1w  = (const float*)d_in[1];
  const float* ln1b  = (const float*)d_in[2];
  const float* ln2w  = (const float*)d_in[3];
  const float* ln2b  = (const float*)d_in[4];
  const float* gatew = (const float*)d_in[5];
  const float* gateb = (const float*)d_in[6];
  const float* valw  = (const float*)d_in[7];
  const float* valb  = (const float*)d_in[8];
  const float* f1w   = (const float*)d_in[9];
  const float* f1b   = (const float*)d_in[10];
  const float* f2w   = (const float*)d_in[11];
  const float* f2b   = (const float*)d_in[12];
  float* out = (float*)d_out;   // doubles as X2 = x + mem scratch

  const size_t MB = 1024u * 1024u;
  const size_t baseNeed = (size_t)(32+32+32+2+2+8+8)*MB + 2u*BATCH*NCHUNK*DIMD*4 + 4096;
  const bool bigT = (baseNeed + 64u*MB) <= ws_size;

  char* ws = (char*)d_ws;
  size_t off = 0;
  auto alloc = [&](size_t bytes) -> char* {
    char* p = ws + off; off += (bytes + 255) & ~(size_t)255; return p;
  };
  unsigned short* H  = (unsigned short*)alloc((size_t)MTOT * DIMD * 2);     // 32 MiB (h / h2)
  unsigned short* G  = (unsigned short*)alloc((size_t)MTOT * DIMD * 2);     // 32 MiB
  unsigned short* V  = (unsigned short*)alloc((size_t)MTOT * DIMD * 2);     // 32 MiB
  if (bigT) alloc(64u * MB);                                                // T extension
  unsigned short* T  = G;  // FFN hidden: bigT -> [16384][4096] over G+V+EXT, else half-chunk
  unsigned short* WGV= (unsigned short*)alloc((size_t)2 * DIMD * DIMD * 2); // stacked [gate;val]
  unsigned short* W1 = (unsigned short*)alloc((size_t)4 * DIMD * DIMD * 2);
  unsigned short* W2 = (unsigned short*)alloc((size_t)4 * DIMD * DIMD * 2);
  float* SG  = (float*)alloc((size_t)BATCH * NCHUNK * DIMD * 4);
  float* SGV = (float*)alloc((size_t)BATCH * NCHUNK * DIMD * 4);

  if (off > ws_size) return;   // graceful fail (absmax mismatch, not a GPU fault)

  // weights -> bf16 (gate rows then val rows stacked into WGV)
  f32_to_bf16_kernel<<<DIMD*DIMD/1024, 256, 0, stream>>>(gatew, WGV, DIMD*DIMD);
  f32_to_bf16_kernel<<<DIMD*DIMD/1024, 256, 0, stream>>>(valw,  WGV + (size_t)DIMD*DIMD, DIMD*DIMD);
  f32_to_bf16_kernel<<<4*DIMD*DIMD/1024, 256, 0, stream>>>(f1w, W1, 4*DIMD*DIMD);
  f32_to_bf16_kernel<<<4*DIMD*DIMD/1024, 256, 0, stream>>>(f2w, W2, 4*DIMD*DIMD);

  // LN1
  ln_kernel<<<MTOT, 256, 0, stream>>>(x, ln1w, ln1b, H);

  // stacked gate|val: one N=2048 GEMM -> G (sigmoid) and V (plain)
  gemm128<5><<<(MTOT/128)*(2048/128), 256, 0, stream>>>(
      H, DIMD, WGV, DIMD, gateb, valb, G, V, 2048, 2048/128, DIMD);

  // chunked scan -> mem -> out = x + mem
  scan_sums  <<<dim3(BATCH*NCHUNK, DIMD/256), 256, 0, stream>>>(G, V, SG, SGV);
  scan_prefix<<<dim3(BATCH, DIMD/256),        256, 0, stream>>>(SG, SGV);
  scan_final <<<dim3(BATCH*NCHUNK, DIMD/256), 256, 0, stream>>>(G, V, SG, SGV, x, out);

  // LN2 (reads out, reuses H)
  ln_kernel<<<MTOT, 256, 0, stream>>>(out, ln2w, ln2b, H);

  if (bigT){
    // FFN1 as 2x N=2048 (B-panel 4MiB = L2-fit/XCD) -> T[16384][4096] column-halves;
    // then one K=4096 FFN2
    for (int c = 0; c < 2; ++c)
      gemm128<2><<<(MTOT/128)*(2048/128), 256, 0, stream>>>(
          H, DIMD, W1 + (size_t)c*2048*DIMD, DIMD, f1b + c*2048, nullptr,
          T + (size_t)c*2048, nullptr, 4*DIMD, 2048/128, DIMD);
    gemm128<3><<<(MTOT/128)*(DIMD/128), 256, 0, stream>>>(
        T, 4*DIMD, W2, 4*DIMD, f2b, nullptr, out, nullptr, DIMD, DIMD/128, 4*DIMD);
  } else {
    // FFN in 2 hidden-dim chunks of 2048 (T aliases G/V, out accumulates)
    for (int c = 0; c < 2; ++c){
      const unsigned short* W1c = W1 + (size_t)c * 2048 * DIMD;   // rows [c*2048, ..)
      const unsigned short* W2c = W2 + (size_t)c * 2048;          // k-columns [c*2048, ..)
      gemm128<2><<<(MTOT/128)*(2048/128), 256, 0, stream>>>(
          H, DIMD, W1c, DIMD, f1b + c*2048, nullptr, T, nullptr, 2048, 2048/128, DIMD);
      if (c == 0)
        gemm128<3><<<(MTOT/128)*(DIMD/128), 256, 0, stream>>>(
            T, 2048, W2c, 4*DIMD, f2b, nullptr, out, nullptr, DIMD, DIMD/128, 2048);
      else
        gemm128<4><<<(MTOT/128)*(DIMD/128), 256, 0, stream>>>(
            T, 2048, W2c, 4*DIMD, nullptr, nullptr, out, nullptr, DIMD, DIMD/128, 2048);
    }
  }
}

// Round 15
// 509.243 us; speedup vs baseline: 1.2506x; 1.2506x over previous
//
#include <hip/hip_runtime.h>
#include <cstdint>
#include <cstddef>

#define DIMD 1024
#define SEQ  4096
#define BATCH 4
#define MTOT (BATCH*SEQ)   // 16384 rows
#define NCHUNK 64          // scan chunks
#define CLEN   64          // chunk length

typedef __attribute__((ext_vector_type(8))) short short8;
typedef __attribute__((ext_vector_type(4))) float floatx4;

__device__ __forceinline__ unsigned short f2bf(float f){
  unsigned u = __float_as_uint(f);
  u += 0x7fffu + ((u >> 16) & 1u);   // RNE
  return (unsigned short)(u >> 16);
}
__device__ __forceinline__ float bf2f(unsigned short u){
  return __uint_as_float((unsigned)u << 16);
}

// hardware-pipe transcendentals (v_exp_f32 is 2^x; v_rcp_f32): ~5 insts vs ~25-45 for libm
__device__ __forceinline__ float fast_sigmoid(float x){
  return __builtin_amdgcn_rcpf(1.f + __builtin_amdgcn_exp2f(-1.442695041f * x));
}
__device__ __forceinline__ float fast_gelu(float x){
  float u = 1.595769122f * x * (1.f + 0.044715f * x * x);
  return x * fast_sigmoid(u);
}

__device__ __forceinline__ void async16(const void* g, void* l){
  __builtin_amdgcn_global_load_lds(
      (const __attribute__((address_space(1))) void*)g,
      (__attribute__((address_space(3))) void*)l, 16, 0, 0);
}

// ---------------- weight fp32 -> bf16 ----------------
__global__ void f32_to_bf16_kernel(const float* __restrict__ in,
                                   unsigned short* __restrict__ out, int n){
  int i = (blockIdx.x * 256 + threadIdx.x) * 4;
  if (i < n){
    float4 v = *(const float4*)(in + i);
    uint2 o;
    o.x = (unsigned)f2bf(v.x) | ((unsigned)f2bf(v.y) << 16);
    o.y = (unsigned)f2bf(v.z) | ((unsigned)f2bf(v.w) << 16);
    *(uint2*)(out + i) = o;
  }
}

// ---------------- LayerNorm (fp32 in -> bf16 out) ----------------
__global__ __launch_bounds__(256)
void ln_kernel(const float* __restrict__ X, const float* __restrict__ w,
               const float* __restrict__ b, unsigned short* __restrict__ H){
  const int row = blockIdx.x;
  const int tid = threadIdx.x;
  const float4 xv = ((const float4*)(X + (size_t)row * DIMD))[tid];
  float s  = xv.x + xv.y + xv.z + xv.w;
  float ss = xv.x*xv.x + xv.y*xv.y + xv.z*xv.z + xv.w*xv.w;
  #pragma unroll
  for (int o = 32; o; o >>= 1){
    s  += __shfl_down(s, o);
    ss += __shfl_down(ss, o);
  }
  __shared__ float ps[4], pss[4], mv[2];
  const int wid = tid >> 6, lane = tid & 63;
  if (lane == 0){ ps[wid] = s; pss[wid] = ss; }
  __syncthreads();
  if (tid == 0){
    float S1 = ps[0]+ps[1]+ps[2]+ps[3];
    float S2 = pss[0]+pss[1]+pss[2]+pss[3];
    float m = S1 * (1.0f / DIMD);
    float var = S2 * (1.0f / DIMD) - m*m;
    mv[0] = m; mv[1] = rsqrtf(var + 1e-5f);
  }
  __syncthreads();
  const float m = mv[0], rs = mv[1];
  const float4 wv = ((const float4*)w)[tid];
  const float4 bv = ((const float4*)b)[tid];
  float o0 = (xv.x - m) * rs * wv.x + bv.x;
  float o1 = (xv.y - m) * rs * wv.y + bv.y;
  float o2 = (xv.z - m) * rs * wv.z + bv.z;
  float o3 = (xv.w - m) * rs * wv.w + bv.w;
  uint2 o;
  o.x = (unsigned)f2bf(o0) | ((unsigned)f2bf(o1) << 16);
  o.y = (unsigned)f2bf(o2) | ((unsigned)f2bf(o3) << 16);
  ((uint2*)(H + (size_t)row * DIMD))[tid] = o;
}

// ------- 256x256 8-wave MFMA GEMM, BK=32, 3-buf register-pipelined counted schedule -------
// (identical to R12 — best measured GEMM structure: 504 us total, MfmaUtil 31.5%)
// EPI: 2 gelu->bf16, 3 acc+bias+out[o]->f32, 4 acc+out[o]->f32,
//      5 stacked gate/val: col<1024 -> sigmoid->Out, else plain->Out2 (both ld 1024)
template<int EPI>
__global__ __launch_bounds__(512, 2)
void gemm256(const unsigned short* __restrict__ A, int lda,
             const unsigned short* __restrict__ Bw, int ldb,
             const float* __restrict__ bias, const float* __restrict__ bias2,
             void* __restrict__ OutP, void* __restrict__ Out2P,
             int ldc, int grid_n, int K)
{
  __shared__ char lds[3 * 32768];       // buf b: A @ b*32768, B @ +16384 (64B rows)
  const int tid = threadIdx.x;
  const int bid = ((int)blockIdx.x & 7) * ((int)gridDim.x >> 3) + ((int)blockIdx.x >> 3);
  const int bm = bid / grid_n, bn = bid % grid_n;
  const int row0 = bm * 256, col0 = bn * 256;
  const int wid = tid >> 6, lane = tid & 63;
  const int wr = wid >> 2, wc = wid & 3;          // 2x4 wave grid, per-wave 128x64
  const int l15 = lane & 15, rq = lane >> 4;

  const int st_sl = (tid & 3) ^ ((tid >> 3) & 3);
  const unsigned short* aP = A  + (size_t)(row0 + (tid >> 2)) * lda + st_sl * 8;
  const unsigned short* bP = Bw + (size_t)(col0 + (tid >> 2)) * ldb + st_sl * 8;
  const int st_off = tid * 16;
  const size_t ldaL = (size_t)lda * 128, ldbL = (size_t)ldb * 128;   // 128-row stride

  const int slp = (rq ^ ((l15 >> 1) & 3)) << 4;
  int offA[8], offB[4];
  #pragma unroll
  for (int m = 0; m < 8; ++m) offA[m] = (wr*128 + m*16 + l15) * 64 + slp;
  #pragma unroll
  for (int n = 0; n < 4; ++n) offB[n] = 16384 + (wc*64 + n*16 + l15) * 64 + slp;

  floatx4 acc[8][4];
  #pragma unroll
  for (int m = 0; m < 8; ++m)
    #pragma unroll
    for (int n = 0; n < 4; ++n)
      acc[m][n] = (floatx4){0.f, 0.f, 0.f, 0.f};

  auto stage = [&](int buf, int kel){      // kel = k0 in elements
    char* base = lds + buf * 32768;
    async16(aP + kel,        base + st_off);
    async16(aP + ldaL + kel, base + 8192  + st_off);
    async16(bP + kel,        base + 16384 + st_off);
    async16(bP + ldbL + kel, base + 24576 + st_off);
  };

  const int nt = K >> 5;
  stage(0, 0); stage(1, 32);                       // kt0, kt1 (8 loads)
  asm volatile("s_waitcnt vmcnt(4)" ::: "memory"); // kt0 landed, kt1 in flight
  asm volatile("s_barrier" ::: "memory");

  int bufi = 0, sbuf = 2, kel = 64;                // stage target (kt+2), k0 elements
  for (int t = 0; t < nt; ++t){
    const char* Lp = lds + bufi * 32768;
    short8 av[8], bv[4];
    #pragma unroll
    for (int m = 0; m < 8; ++m) av[m] = *(const short8*)(Lp + offA[m]);
    #pragma unroll
    for (int n = 0; n < 4; ++n) bv[n] = *(const short8*)(Lp + offB[n]);

    stage(sbuf, kel);                              // kt+2 (OOB-safe garbage at tail)
    kel += 32;

    __builtin_amdgcn_s_setprio(1);
    #pragma unroll
    for (int m = 0; m < 8; ++m)
      #pragma unroll
      for (int n = 0; n < 4; ++n)
        acc[m][n] = __builtin_amdgcn_mfma_f32_16x16x32_bf16(av[m], bv[n], acc[m][n], 0, 0, 0);
    __builtin_amdgcn_s_setprio(0);

    asm volatile("s_barrier" ::: "memory");            // all waves done reading buf[kt%3]
    asm volatile("s_waitcnt vmcnt(4)" ::: "memory");   // kt+1 landed (kt+2 still flying)
    asm volatile("s_barrier" ::: "memory");            // collectively visible
    if (++bufi == 3) bufi = 0;
    if (++sbuf == 3) sbuf = 0;
  }

  // drain tail garbage DMA before reusing LDS as epilogue slab
  asm volatile("s_waitcnt vmcnt(0)" ::: "memory");
  asm volatile("s_barrier" ::: "memory");

  if constexpr (EPI == 2 || EPI == 5){
    // LDS-repack epilogue: wave-private 4 KiB slab -> 128B-coalesced dwordx4 stores
    char* slab = lds + wid * 4096;
    unsigned short* dst; int colw; int ldout; bool sigm = false;
    const float* bsel;
    if constexpr (EPI == 5){
      const int c0 = col0 + wc * 64;
      if (c0 < 1024){ dst = (unsigned short*)OutP;  colw = c0;        bsel = bias;  sigm = true;  }
      else          { dst = (unsigned short*)Out2P; colw = c0 - 1024; bsel = bias2; sigm = false; }
      ldout = 1024;
    } else {
      dst = (unsigned short*)OutP; colw = col0 + wc * 64; bsel = bias; ldout = ldc;
    }
    const int rdrow = lane >> 3;
    const int rdoff  = rdrow * 128 + (((lane & 7) ^ (rdrow & 7)) << 4);
    const int rdoff2 = (rdrow + 8) * 128 + (((lane & 7) ^ ((rdrow + 8) & 7)) << 4);
    const int rdsl = (lane & 7) * 16;
    #pragma unroll
    for (int m = 0; m < 8; ++m){
      #pragma unroll
      for (int n = 0; n < 4; ++n){
        const float bs = bsel[colw + n*16 + l15];
        const int cchunk = n*2 + (l15 >> 3);
        #pragma unroll
        for (int j = 0; j < 4; ++j){
          const float val = acc[m][n][j] + bs;
          float r;
          if constexpr (EPI == 2){
            r = fast_gelu(val);
          } else {
            r = sigm ? fast_sigmoid(val) : val;
          }
          const int rr = rq*4 + j;
          *(unsigned short*)(slab + rr*128 + ((cchunk ^ (rr & 7)) << 4) + (l15 & 7)*2) = f2bf(r);
        }
      }
      asm volatile("s_waitcnt lgkmcnt(0)" ::: "memory");   // slab writes landed (wave-local)
      uint4 w0 = *(const uint4*)(slab + rdoff);
      uint4 w1 = *(const uint4*)(slab + rdoff2);
      asm volatile("s_waitcnt lgkmcnt(0)" ::: "memory");   // reads done before next m overwrites
      const int growb = row0 + wr * 128 + m * 16;
      *(uint4*)((char*)(dst + (size_t)(growb + rdrow) * ldout + colw) + rdsl) = w0;
      *(uint4*)((char*)(dst + (size_t)(growb + rdrow + 8) * ldout + colw) + rdsl) = w1;
    }
  } else {
    // f32 RMW epilogue
    #pragma unroll
    for (int n = 0; n < 4; ++n){
      const int col = col0 + wc * 64 + n * 16 + l15;
      const float bs = (EPI == 4) ? 0.f : bias[col];
      #pragma unroll
      for (int m = 0; m < 8; ++m){
        const int rowb = row0 + wr * 128 + m * 16 + rq * 4;
        #pragma unroll
        for (int j = 0; j < 4; ++j){
          const size_t o = (size_t)(rowb + j) * ldc + col;
          float* O = (float*)OutP;
          O[o] = acc[m][n][j] + bs + O[o];
        }
      }
    }
  }
}

// ------- 3-phase chunked scan, G13-vectorized: 4 d-lanes/thread, uint2 bf16 loads -------
__global__ __launch_bounds__(256)
void scan_sums(const unsigned short* __restrict__ G, const unsigned short* __restrict__ V,
               float* __restrict__ SG, float* __restrict__ SGV){
  const int bc = blockIdx.x;                 // b*NCHUNK + c
  const int d0 = (blockIdx.y * 256 + threadIdx.x) * 4;
  const int b = bc >> 6, c = bc & 63;
  size_t base = ((size_t)b * SEQ + (size_t)c * CLEN) * DIMD + d0;
  float sg[4] = {0.f,0.f,0.f,0.f}, sgv[4] = {0.f,0.f,0.f,0.f};
  for (int i = 0; i < CLEN; ++i){
    uint2 gv = *(const uint2*)(G + base + (size_t)i * DIMD);
    uint2 vv = *(const uint2*)(V + base + (size_t)i * DIMD);
    float g0 = bf2f((unsigned short)(gv.x & 0xffff)), g1 = bf2f((unsigned short)(gv.x >> 16));
    float g2 = bf2f((unsigned short)(gv.y & 0xffff)), g3 = bf2f((unsigned short)(gv.y >> 16));
    float v0 = bf2f((unsigned short)(vv.x & 0xffff)), v1 = bf2f((unsigned short)(vv.x >> 16));
    float v2 = bf2f((unsigned short)(vv.y & 0xffff)), v3 = bf2f((unsigned short)(vv.y >> 16));
    sg[0] += g0; sgv[0] += g0*v0;
    sg[1] += g1; sgv[1] += g1*v1;
    sg[2] += g2; sgv[2] += g2*v2;
    sg[3] += g3; sgv[3] += g3*v3;
  }
  *(float4*)(SG  + (size_t)bc * DIMD + d0) = make_float4(sg[0],sg[1],sg[2],sg[3]);
  *(float4*)(SGV + (size_t)bc * DIMD + d0) = make_float4(sgv[0],sgv[1],sgv[2],sgv[3]);
}

__global__ __launch_bounds__(256)
void scan_prefix(float* __restrict__ SG, float* __restrict__ SGV){
  const int b  = blockIdx.x;
  const int d0 = (blockIdx.y * 256 + threadIdx.x) * 4;
  float4 rg = make_float4(0.f,0.f,0.f,0.f), rgv = make_float4(0.f,0.f,0.f,0.f);
  for (int c = 0; c < NCHUNK; ++c){
    size_t i = ((size_t)(b * NCHUNK + c)) * DIMD + d0;
    float4 tg = *(float4*)(SG + i), tv = *(float4*)(SGV + i);
    *(float4*)(SG + i) = rg; *(float4*)(SGV + i) = rgv;
    rg.x += tg.x; rg.y += tg.y; rg.z += tg.z; rg.w += tg.w;
    rgv.x += tv.x; rgv.y += tv.y; rgv.z += tv.z; rgv.w += tv.w;
  }
}

__global__ __launch_bounds__(256)
void scan_final(const unsigned short* __restrict__ G, const unsigned short* __restrict__ V,
                const float* __restrict__ SG, const float* __restrict__ SGV,
                const float* __restrict__ X, float* __restrict__ X2){
  const int bc = blockIdx.x;
  const int d0 = (blockIdx.y * 256 + threadIdx.x) * 4;
  const int b = bc >> 6, c = bc & 63;
  size_t base = ((size_t)b * SEQ + (size_t)c * CLEN) * DIMD + d0;
  float4 rg  = *(const float4*)(SG  + (size_t)bc * DIMD + d0);
  float4 rgv = *(const float4*)(SGV + (size_t)bc * DIMD + d0);
  float rgA[4]  = {rg.x, rg.y, rg.z, rg.w};
  float rgvA[4] = {rgv.x, rgv.y, rgv.z, rgv.w};
  for (int i = 0; i < CLEN; ++i){
    size_t idx = base + (size_t)i * DIMD;
    uint2 gv = *(const uint2*)(G + idx);
    uint2 vv = *(const uint2*)(V + idx);
    float4 xv = *(const float4*)(X + idx);
    float gA[4] = { bf2f((unsigned short)(gv.x & 0xffff)), bf2f((unsigned short)(gv.x >> 16)),
                    bf2f((unsigned short)(gv.y & 0xffff)), bf2f((unsigned short)(gv.y >> 16)) };
    float vA[4] = { bf2f((unsigned short)(vv.x & 0xffff)), bf2f((unsigned short)(vv.x >> 16)),
                    bf2f((unsigned short)(vv.y & 0xffff)), bf2f((unsigned short)(vv.y >> 16)) };
    const int s = c * CLEN + i;
    const float pf = (float)(s + 1) * (1.0f / SEQ) + 0.1f;
    float o[4];
    #pragma unroll
    for (int k = 0; k < 4; ++k){
      rgA[k]  += gA[k];
      rgvA[k] += gA[k] * vA[k];
      o[k] = rgvA[k] * rsqrtf((rgA[k] + 1e-6f) * pf);
    }
    *(float4*)(X2 + idx) = make_float4(xv.x + o[0], xv.y + o[1], xv.z + o[2], xv.w + o[3]);
  }
}

extern "C" void kernel_launch(void* const* d_in, const int* in_sizes, int n_in,
                              void* d_out, int out_size, void* d_ws, size_t ws_size,
                              hipStream_t stream)
{
  const float* x     = (const float*)d_in[0];
  const float* ln1w  = (const float*)d_in[1];
  const float* ln1b  = (const float*)d_in[2];
  const float* ln2w  = (const float*)d_in[3];
  const float* ln2b  = (const float*)d_in[4];
  const float* gatew = (const float*)d_in[5];
  const float* gateb = (const float*)d_in[6];
  const float* valw  = (const float*)d_in[7];
  const float* valb  = (const float*)d_in[8];
  const float* f1w   = (const float*)d_in[9];
  const float* f1b   = (const float*)d_in[10];
  const float* f2w   = (const float*)d_in[11];
  const float* f2b   = (const float*)d_in[12];
  float* out = (float*)d_out;   // doubles as X2 = x + mem scratch

  const size_t MB = 1024u * 1024u;
  const size_t baseNeed = (size_t)(32+32+32+2+2+8+8)*MB + 2u*BATCH*NCHUNK*DIMD*4 + 4096;
  const bool bigT = (baseNeed + 64u*MB) <= ws_size;

  char* ws = (char*)d_ws;
  size_t off = 0;
  auto alloc = [&](size_t bytes) -> char* {
    char* p = ws + off; off += (bytes + 255) & ~(size_t)255; return p;
  };
  unsigned short* H  = (unsigned short*)alloc((size_t)MTOT * DIMD * 2);     // 32 MiB (h / h2)
  unsigned short* G  = (unsigned short*)alloc((size_t)MTOT * DIMD * 2);     // 32 MiB
  unsigned short* V  = (unsigned short*)alloc((size_t)MTOT * DIMD * 2);     // 32 MiB
  if (bigT) alloc(64u * MB);                                                // T extension
  unsigned short* T  = G;  // FFN hidden: bigT -> [16384][4096] over G+V+EXT, else half-chunk
  unsigned short* WGV= (unsigned short*)alloc((size_t)2 * DIMD * DIMD * 2); // stacked [gate;val]
  unsigned short* W1 = (unsigned short*)alloc((size_t)4 * DIMD * DIMD * 2);
  unsigned short* W2 = (unsigned short*)alloc((size_t)4 * DIMD * DIMD * 2);
  float* SG  = (float*)alloc((size_t)BATCH * NCHUNK * DIMD * 4);
  float* SGV = (float*)alloc((size_t)BATCH * NCHUNK * DIMD * 4);

  if (off > ws_size) return;   // graceful fail (absmax mismatch, not a GPU fault)

  // weights -> bf16 (gate rows then val rows stacked into WGV)
  f32_to_bf16_kernel<<<DIMD*DIMD/1024, 256, 0, stream>>>(gatew, WGV, DIMD*DIMD);
  f32_to_bf16_kernel<<<DIMD*DIMD/1024, 256, 0, stream>>>(valw,  WGV + (size_t)DIMD*DIMD, DIMD*DIMD);
  f32_to_bf16_kernel<<<4*DIMD*DIMD/1024, 256, 0, stream>>>(f1w, W1, 4*DIMD*DIMD);
  f32_to_bf16_kernel<<<4*DIMD*DIMD/1024, 256, 0, stream>>>(f2w, W2, 4*DIMD*DIMD);

  // LN1
  ln_kernel<<<MTOT, 256, 0, stream>>>(x, ln1w, ln1b, H);

  // stacked gate|val: one N=2048 GEMM -> G (sigmoid) and V (plain)
  gemm256<5><<<(MTOT/256)*(2048/256), 512, 0, stream>>>(
      H, DIMD, WGV, DIMD, gateb, valb, G, V, 2048, 2048/256, DIMD);

  // chunked scan (vectorized: 4 d/thread) -> mem -> out = x + mem
  scan_sums  <<<dim3(BATCH*NCHUNK, DIMD/1024), 256, 0, stream>>>(G, V, SG, SGV);
  scan_prefix<<<dim3(BATCH, DIMD/1024),        256, 0, stream>>>(SG, SGV);
  scan_final <<<dim3(BATCH*NCHUNK, DIMD/1024), 256, 0, stream>>>(G, V, SG, SGV, x, out);

  // LN2 (reads out, reuses H)
  ln_kernel<<<MTOT, 256, 0, stream>>>(out, ln2w, ln2b, H);

  if (bigT){
    // FFN1: single N=4096 GEMM -> T[16384][4096], then one K=4096 FFN2
    gemm256<2><<<(MTOT/256)*(4096/256), 512, 0, stream>>>(
        H, DIMD, W1, DIMD, f1b, nullptr, T, nullptr, 4*DIMD, 4096/256, DIMD);
    gemm256<3><<<(MTOT/256)*(DIMD/256), 512, 0, stream>>>(
        T, 4*DIMD, W2, 4*DIMD, f2b, nullptr, out, nullptr, DIMD, DIMD/256, 4*DIMD);
  } else {
    // FFN in 2 hidden-dim chunks of 2048 (T aliases G/V, out accumulates)
    for (int c = 0; c < 2; ++c){
      const unsigned short* W1c = W1 + (size_t)c * 2048 * DIMD;   // rows [c*2048, ..)
      const unsigned short* W2c = W2 + (size_t)c * 2048;          // k-columns [c*2048, ..)
      gemm256<2><<<(MTOT/256)*(2048/256), 512, 0, stream>>>(
          H, DIMD, W1c, DIMD, f1b + c*2048, nullptr, T, nullptr, 2048, 2048/256, DIMD);
      if (c == 0)
        gemm256<3><<<(MTOT/256)*(DIMD/256), 512, 0, stream>>>(
            T, 2048, W2c, 4*DIMD, f2b, nullptr, out, nullptr, DIMD, DIMD/256, 2048);
      else
        gemm256<4><<<(MTOT/256)*(DIMD/256), 512, 0, stream>>>(
            T, 2048, W2c, 4*DIMD, nullptr, nullptr, out, nullptr, DIMD, DIMD/256, 2048);
    }
  }
}

// Round 16
// 498.699 us; speedup vs baseline: 1.2770x; 1.0211x over previous
//
#include <hip/hip_runtime.h>
#include <cstdint>
#include <cstddef>

#define DIMD 1024
#define SEQ  4096
#define BATCH 4
#define MTOT (BATCH*SEQ)   // 16384 rows
#define NCHUNK 64          // scan chunks
#define CLEN   64          // chunk length

typedef __attribute__((ext_vector_type(8))) short short8;
typedef __attribute__((ext_vector_type(4))) float floatx4;

__device__ __forceinline__ unsigned short f2bf(float f){
  unsigned u = __float_as_uint(f);
  u += 0x7fffu + ((u >> 16) & 1u);   // RNE
  return (unsigned short)(u >> 16);
}
__device__ __forceinline__ float bf2f(unsigned short u){
  return __uint_as_float((unsigned)u << 16);
}

// hardware-pipe transcendentals
__device__ __forceinline__ float fast_sigmoid(float x){
  return __builtin_amdgcn_rcpf(1.f + __builtin_amdgcn_exp2f(-1.442695041f * x));
}
__device__ __forceinline__ float fast_gelu(float x){
  float u = 1.595769122f * x * (1.f + 0.044715f * x * x);
  return x * fast_sigmoid(u);
}

__device__ __forceinline__ void async16(const void* g, void* l){
  __builtin_amdgcn_global_load_lds(
      (const __attribute__((address_space(1))) void*)g,
      (__attribute__((address_space(3))) void*)l, 16, 0, 0);
}

// ---------------- weight fp32 -> bf16 ----------------
__global__ void f32_to_bf16_kernel(const float* __restrict__ in,
                                   unsigned short* __restrict__ out, int n){
  int i = (blockIdx.x * 256 + threadIdx.x) * 4;
  if (i < n){
    float4 v = *(const float4*)(in + i);
    uint2 o;
    o.x = (unsigned)f2bf(v.x) | ((unsigned)f2bf(v.y) << 16);
    o.y = (unsigned)f2bf(v.z) | ((unsigned)f2bf(v.w) << 16);
    *(uint2*)(out + i) = o;
  }
}

// ---------------- LayerNorm (fp32 in -> bf16 out) ----------------
__global__ __launch_bounds__(256)
void ln_kernel(const float* __restrict__ X, const float* __restrict__ w,
               const float* __restrict__ b, unsigned short* __restrict__ H){
  const int row = blockIdx.x;
  const int tid = threadIdx.x;
  const float4 xv = ((const float4*)(X + (size_t)row * DIMD))[tid];
  float s  = xv.x + xv.y + xv.z + xv.w;
  float ss = xv.x*xv.x + xv.y*xv.y + xv.z*xv.z + xv.w*xv.w;
  #pragma unroll
  for (int o = 32; o; o >>= 1){
    s  += __shfl_down(s, o);
    ss += __shfl_down(ss, o);
  }
  __shared__ float ps[4], pss[4], mv[2];
  const int wid = tid >> 6, lane = tid & 63;
  if (lane == 0){ ps[wid] = s; pss[wid] = ss; }
  __syncthreads();
  if (tid == 0){
    float S1 = ps[0]+ps[1]+ps[2]+ps[3];
    float S2 = pss[0]+pss[1]+pss[2]+pss[3];
    float m = S1 * (1.0f / DIMD);
    float var = S2 * (1.0f / DIMD) - m*m;
    mv[0] = m; mv[1] = rsqrtf(var + 1e-5f);
  }
  __syncthreads();
  const float m = mv[0], rs = mv[1];
  const float4 wv = ((const float4*)w)[tid];
  const float4 bv = ((const float4*)b)[tid];
  float o0 = (xv.x - m) * rs * wv.x + bv.x;
  float o1 = (xv.y - m) * rs * wv.y + bv.y;
  float o2 = (xv.z - m) * rs * wv.z + bv.z;
  float o3 = (xv.w - m) * rs * wv.w + bv.w;
  uint2 o;
  o.x = (unsigned)f2bf(o0) | ((unsigned)f2bf(o1) << 16);
  o.y = (unsigned)f2bf(o2) | ((unsigned)f2bf(o3) << 16);
  ((uint2*)(H + (size_t)row * DIMD))[tid] = o;
}

// ------- 256x256 8-wave GEMM, BK=32, 3-buf, m201-style 4-phase fine interleave -------
// Per K-tile: 4 phases, each {Gray-reuse ds_reads (6/2/4/0); stage 1 DMA-unit of tile t+2;
// s_barrier; lgkmcnt(0); setprio(1); 8 MFMA (one C-quadrant); setprio(0); s_barrier}.
// Counted vmcnt(4) only at phase 3 (tile t+1 = oldest 4 of 8 outstanding). Never vmcnt(0)
// in loop. Swizzle (0-conflict) + XCD swizzle + slab epilogue identical to R12.
// EPI: 2 gelu->bf16, 3 acc+bias+out[o]->f32, 4 acc+out[o]->f32,
//      5 stacked gate/val: col<1024 -> sigmoid->Out, else plain->Out2 (both ld 1024)
template<int EPI>
__global__ __launch_bounds__(512, 2)
void gemm256(const unsigned short* __restrict__ A, int lda,
             const unsigned short* __restrict__ Bw, int ldb,
             const float* __restrict__ bias, const float* __restrict__ bias2,
             void* __restrict__ OutP, void* __restrict__ Out2P,
             int ldc, int grid_n, int K)
{
  __shared__ char lds[3 * 32768];       // buf b: A @ b*32768, B @ +16384 (64B rows)
  const int tid = threadIdx.x;
  const int bid = ((int)blockIdx.x & 7) * ((int)gridDim.x >> 3) + ((int)blockIdx.x >> 3);
  const int bm = bid / grid_n, bn = bid % grid_n;
  const int row0 = bm * 256, col0 = bn * 256;
  const int wid = tid >> 6, lane = tid & 63;
  const int wr = wid >> 2, wc = wid & 3;          // 2x4 wave grid, per-wave 128x64
  const int l15 = lane & 15, rq = lane >> 4;

  const int st_sl = (tid & 3) ^ ((tid >> 3) & 3);
  const unsigned short* aP = A  + (size_t)(row0 + (tid >> 2)) * lda + st_sl * 8;
  const unsigned short* bP = Bw + (size_t)(col0 + (tid >> 2)) * ldb + st_sl * 8;
  const int st_off = tid * 16;
  const size_t ldaL = (size_t)lda * 128, ldbL = (size_t)ldb * 128;   // 128-row stride

  const int slp = (rq ^ ((l15 >> 1) & 3)) << 4;
  int offA[8], offB[4];
  #pragma unroll
  for (int m = 0; m < 8; ++m) offA[m] = (wr*128 + m*16 + l15) * 64 + slp;
  #pragma unroll
  for (int n = 0; n < 4; ++n) offB[n] = 16384 + (wc*64 + n*16 + l15) * 64 + slp;

  floatx4 acc[8][4];
  #pragma unroll
  for (int m = 0; m < 8; ++m)
    #pragma unroll
    for (int n = 0; n < 4; ++n)
      acc[m][n] = (floatx4){0.f, 0.f, 0.f, 0.f};

  // DMA units 0..3 of a tile: A rows 0-127, A rows 128-255, B rows 0-127, B rows 128-255
  auto stage1 = [&](int buf, int kel, int unit){
    char* base = lds + buf * 32768;
    if      (unit == 0) async16(aP + kel,        base + st_off);
    else if (unit == 1) async16(aP + ldaL + kel, base + 8192  + st_off);
    else if (unit == 2) async16(bP + kel,        base + 16384 + st_off);
    else                async16(bP + ldbL + kel, base + 24576 + st_off);
  };
  auto stage4 = [&](int buf, int kel){
    #pragma unroll
    for (int u = 0; u < 4; ++u) stage1(buf, kel, u);
  };

  const int nt = K >> 5;
  stage4(0, 0); stage4(1, 32);                     // tiles 0,1 (8 issues)
  asm volatile("s_waitcnt vmcnt(4)" ::: "memory"); // tile 0 landed; tile 1 in flight
  asm volatile("s_barrier" ::: "memory");

  int bufi = 0, sbuf = 2;
  for (int t = 0; t < nt; ++t){
    const char* Lp = lds + bufi * 32768;
    const int kel2 = ((t + 2 < nt) ? t + 2 : nt - 1) << 5;   // clamped tail re-stage
    short8 aLo[4], aHi[4], bLo[2], bHi[2];

    // ---- phase 0: quadrant (mLo, nLo) ---- 6 reads + 1 stage
    #pragma unroll
    for (int m = 0; m < 4; ++m) aLo[m] = *(const short8*)(Lp + offA[m]);
    bLo[0] = *(const short8*)(Lp + offB[0]);
    bLo[1] = *(const short8*)(Lp + offB[1]);
    stage1(sbuf, kel2, 0);
    asm volatile("s_barrier" ::: "memory");
    asm volatile("s_waitcnt lgkmcnt(0)" ::: "memory");
    __builtin_amdgcn_s_setprio(1);
    #pragma unroll
    for (int m = 0; m < 4; ++m)
      #pragma unroll
      for (int n = 0; n < 2; ++n)
        acc[m][n] = __builtin_amdgcn_mfma_f32_16x16x32_bf16(aLo[m], bLo[n], acc[m][n], 0, 0, 0);
    __builtin_amdgcn_s_setprio(0);
    asm volatile("s_barrier" ::: "memory");

    // ---- phase 1: quadrant (mLo, nHi) ---- 2 reads + 1 stage
    bHi[0] = *(const short8*)(Lp + offB[2]);
    bHi[1] = *(const short8*)(Lp + offB[3]);
    stage1(sbuf, kel2, 1);
    asm volatile("s_barrier" ::: "memory");
    asm volatile("s_waitcnt lgkmcnt(0)" ::: "memory");
    __builtin_amdgcn_s_setprio(1);
    #pragma unroll
    for (int m = 0; m < 4; ++m)
      #pragma unroll
      for (int n = 0; n < 2; ++n)
        acc[m][2+n] = __builtin_amdgcn_mfma_f32_16x16x32_bf16(aLo[m], bHi[n], acc[m][2+n], 0, 0, 0);
    __builtin_amdgcn_s_setprio(0);
    asm volatile("s_barrier" ::: "memory");

    // ---- phase 2: quadrant (mHi, nHi) ---- 4 reads + 1 stage
    #pragma unroll
    for (int m = 0; m < 4; ++m) aHi[m] = *(const short8*)(Lp + offA[4+m]);
    stage1(sbuf, kel2, 2);
    asm volatile("s_barrier" ::: "memory");
    asm volatile("s_waitcnt lgkmcnt(0)" ::: "memory");
    __builtin_amdgcn_s_setprio(1);
    #pragma unroll
    for (int m = 0; m < 4; ++m)
      #pragma unroll
      for (int n = 0; n < 2; ++n)
        acc[4+m][2+n] = __builtin_amdgcn_mfma_f32_16x16x32_bf16(aHi[m], bHi[n], acc[4+m][2+n], 0, 0, 0);
    __builtin_amdgcn_s_setprio(0);
    asm volatile("s_barrier" ::: "memory");

    // ---- phase 3: quadrant (mHi, nLo) ---- 0 reads + 1 stage + counted vmcnt
    stage1(sbuf, kel2, 3);
    asm volatile("s_barrier" ::: "memory");
    __builtin_amdgcn_s_setprio(1);
    #pragma unroll
    for (int m = 0; m < 4; ++m)
      #pragma unroll
      for (int n = 0; n < 2; ++n)
        acc[4+m][n] = __builtin_amdgcn_mfma_f32_16x16x32_bf16(aHi[m], bLo[n], acc[4+m][n], 0, 0, 0);
    __builtin_amdgcn_s_setprio(0);
    asm volatile("s_waitcnt vmcnt(4)" ::: "memory");   // tile t+1 landed (t+2 still flying)
    asm volatile("s_barrier" ::: "memory");

    if (++bufi == 3) bufi = 0;
    if (++sbuf == 3) sbuf = 0;
  }

  // drain tail DMA before reusing LDS as epilogue slab
  asm volatile("s_waitcnt vmcnt(0)" ::: "memory");
  asm volatile("s_barrier" ::: "memory");

  if constexpr (EPI == 2 || EPI == 5){
    // LDS-repack epilogue: wave-private 4 KiB slab -> 128B-coalesced dwordx4 stores
    char* slab = lds + wid * 4096;
    unsigned short* dst; int colw; int ldout; bool sigm = false;
    const float* bsel;
    if constexpr (EPI == 5){
      const int c0 = col0 + wc * 64;
      if (c0 < 1024){ dst = (unsigned short*)OutP;  colw = c0;        bsel = bias;  sigm = true;  }
      else          { dst = (unsigned short*)Out2P; colw = c0 - 1024; bsel = bias2; sigm = false; }
      ldout = 1024;
    } else {
      dst = (unsigned short*)OutP; colw = col0 + wc * 64; bsel = bias; ldout = ldc;
    }
    const int rdrow = lane >> 3;
    const int rdoff  = rdrow * 128 + (((lane & 7) ^ (rdrow & 7)) << 4);
    const int rdoff2 = (rdrow + 8) * 128 + (((lane & 7) ^ ((rdrow + 8) & 7)) << 4);
    const int rdsl = (lane & 7) * 16;
    #pragma unroll
    for (int m = 0; m < 8; ++m){
      #pragma unroll
      for (int n = 0; n < 4; ++n){
        const float bs = bsel[colw + n*16 + l15];
        const int cchunk = n*2 + (l15 >> 3);
        #pragma unroll
        for (int j = 0; j < 4; ++j){
          const float val = acc[m][n][j] + bs;
          float r;
          if constexpr (EPI == 2){
            r = fast_gelu(val);
          } else {
            r = sigm ? fast_sigmoid(val) : val;
          }
          const int rr = rq*4 + j;
          *(unsigned short*)(slab + rr*128 + ((cchunk ^ (rr & 7)) << 4) + (l15 & 7)*2) = f2bf(r);
        }
      }
      asm volatile("s_waitcnt lgkmcnt(0)" ::: "memory");   // slab writes landed (wave-local)
      uint4 w0 = *(const uint4*)(slab + rdoff);
      uint4 w1 = *(const uint4*)(slab + rdoff2);
      asm volatile("s_waitcnt lgkmcnt(0)" ::: "memory");   // reads done before next m overwrites
      const int growb = row0 + wr * 128 + m * 16;
      *(uint4*)((char*)(dst + (size_t)(growb + rdrow) * ldout + colw) + rdsl) = w0;
      *(uint4*)((char*)(dst + (size_t)(growb + rdrow + 8) * ldout + colw) + rdsl) = w1;
    }
  } else {
    // f32 RMW epilogue
    #pragma unroll
    for (int n = 0; n < 4; ++n){
      const int col = col0 + wc * 64 + n * 16 + l15;
      const float bs = (EPI == 4) ? 0.f : bias[col];
      #pragma unroll
      for (int m = 0; m < 8; ++m){
        const int rowb = row0 + wr * 128 + m * 16 + rq * 4;
        #pragma unroll
        for (int j = 0; j < 4; ++j){
          const size_t o = (size_t)(rowb + j) * ldc + col;
          float* O = (float*)OutP;
          O[o] = acc[m][n][j] + bs + O[o];
        }
      }
    }
  }
}

// ---------------- 3-phase chunked scan over sequence (bf16 G/V) — R12 form ----------------
__global__ __launch_bounds__(256)
void scan_sums(const unsigned short* __restrict__ G, const unsigned short* __restrict__ V,
               float* __restrict__ SG, float* __restrict__ SGV){
  const int bc = blockIdx.x;                 // b*NCHUNK + c
  const int d  = blockIdx.y * 256 + threadIdx.x;
  const int b = bc >> 6, c = bc & 63;
  size_t base = ((size_t)b * SEQ + (size_t)c * CLEN) * DIMD + d;
  float sg = 0.f, sgv = 0.f;
  for (int i = 0; i < CLEN; ++i){
    float g = bf2f(G[base + (size_t)i * DIMD]);
    float v = bf2f(V[base + (size_t)i * DIMD]);
    sg += g; sgv += g * v;
  }
  SG[(size_t)bc * DIMD + d] = sg;
  SGV[(size_t)bc * DIMD + d] = sgv;
}

__global__ __launch_bounds__(256)
void scan_prefix(float* __restrict__ SG, float* __restrict__ SGV){
  const int b = blockIdx.x;
  const int d = blockIdx.y * 256 + threadIdx.x;
  float rg = 0.f, rgv = 0.f;
  for (int c = 0; c < NCHUNK; ++c){
    size_t i = ((size_t)(b * NCHUNK + c)) * DIMD + d;
    float tg = SG[i], tv = SGV[i];
    SG[i] = rg; SGV[i] = rgv;
    rg += tg; rgv += tv;
  }
}

__global__ __launch_bounds__(256)
void scan_final(const unsigned short* __restrict__ G, const unsigned short* __restrict__ V,
                const float* __restrict__ SG, const float* __restrict__ SGV,
                const float* __restrict__ X, float* __restrict__ X2){
  const int bc = blockIdx.x;
  const int d  = blockIdx.y * 256 + threadIdx.x;
  const int b = bc >> 6, c = bc & 63;
  size_t base = ((size_t)b * SEQ + (size_t)c * CLEN) * DIMD + d;
  float rg  = SG[(size_t)bc * DIMD + d];
  float rgv = SGV[(size_t)bc * DIMD + d];
  for (int i = 0; i < CLEN; ++i){
    size_t idx = base + (size_t)i * DIMD;
    float g = bf2f(G[idx]), v = bf2f(V[idx]);
    rg += g; rgv += g * v;
    int s = c * CLEN + i;
    float pf = (float)(s + 1) * (1.0f / SEQ) + 0.1f;
    float mem = rgv * rsqrtf((rg + 1e-6f) * pf);
    X2[idx] = X[idx] + mem;
  }
}

extern "C" void kernel_launch(void* const* d_in, const int* in_sizes, int n_in,
                              void* d_out, int out_size, void* d_ws, size_t ws_size,
                              hipStream_t stream)
{
  const float* x     = (const float*)d_in[0];
  const float* ln1w  = (const float*)d_in[1];
  const float* ln1b  = (const float*)d_in[2];
  const float* ln2w  = (const float*)d_in[3];
  const float* ln2b  = (const float*)d_in[4];
  const float* gatew = (const float*)d_in[5];
  const float* gateb = (const float*)d_in[6];
  const float* valw  = (const float*)d_in[7];
  const float* valb  = (const float*)d_in[8];
  const float* f1w   = (const float*)d_in[9];
  const float* f1b   = (const float*)d_in[10];
  const float* f2w   = (const float*)d_in[11];
  const float* f2b   = (const float*)d_in[12];
  float* out = (float*)d_out;   // doubles as X2 = x + mem scratch

  const size_t MB = 1024u * 1024u;
  const size_t baseNeed = (size_t)(32+32+32+2+2+8+8)*MB + 2u*BATCH*NCHUNK*DIMD*4 + 4096;
  const bool bigT = (baseNeed + 64u*MB) <= ws_size;

  char* ws = (char*)d_ws;
  size_t off = 0;
  auto alloc = [&](size_t bytes) -> char* {
    char* p = ws + off; off += (bytes + 255) & ~(size_t)255; return p;
  };
  unsigned short* H  = (unsigned short*)alloc((size_t)MTOT * DIMD * 2);     // 32 MiB (h / h2)
  unsigned short* G  = (unsigned short*)alloc((size_t)MTOT * DIMD * 2);     // 32 MiB
  unsigned short* V  = (unsigned short*)alloc((size_t)MTOT * DIMD * 2);     // 32 MiB
  if (bigT) alloc(64u * MB);                                                // T extension
  unsigned short* T  = G;  // FFN hidden: bigT -> [16384][4096] over G+V+EXT, else half-chunk
  unsigned short* WGV= (unsigned short*)alloc((size_t)2 * DIMD * DIMD * 2); // stacked [gate;val]
  unsigned short* W1 = (unsigned short*)alloc((size_t)4 * DIMD * DIMD * 2);
  unsigned short* W2 = (unsigned short*)alloc((size_t)4 * DIMD * DIMD * 2);
  float* SG  = (float*)alloc((size_t)BATCH * NCHUNK * DIMD * 4);
  float* SGV = (float*)alloc((size_t)BATCH * NCHUNK * DIMD * 4);

  if (off > ws_size) return;   // graceful fail (absmax mismatch, not a GPU fault)

  // weights -> bf16 (gate rows then val rows stacked into WGV)
  f32_to_bf16_kernel<<<DIMD*DIMD/1024, 256, 0, stream>>>(gatew, WGV, DIMD*DIMD);
  f32_to_bf16_kernel<<<DIMD*DIMD/1024, 256, 0, stream>>>(valw,  WGV + (size_t)DIMD*DIMD, DIMD*DIMD);
  f32_to_bf16_kernel<<<4*DIMD*DIMD/1024, 256, 0, stream>>>(f1w, W1, 4*DIMD*DIMD);
  f32_to_bf16_kernel<<<4*DIMD*DIMD/1024, 256, 0, stream>>>(f2w, W2, 4*DIMD*DIMD);

  // LN1
  ln_kernel<<<MTOT, 256, 0, stream>>>(x, ln1w, ln1b, H);

  // stacked gate|val: one N=2048 GEMM -> G (sigmoid) and V (plain)
  gemm256<5><<<(MTOT/256)*(2048/256), 512, 0, stream>>>(
      H, DIMD, WGV, DIMD, gateb, valb, G, V, 2048, 2048/256, DIMD);

  // chunked scan -> mem -> out = x + mem
  scan_sums  <<<dim3(BATCH*NCHUNK, DIMD/256), 256, 0, stream>>>(G, V, SG, SGV);
  scan_prefix<<<dim3(BATCH, DIMD/256),        256, 0, stream>>>(SG, SGV);
  scan_final <<<dim3(BATCH*NCHUNK, DIMD/256), 256, 0, stream>>>(G, V, SG, SGV, x, out);

  // LN2 (reads out, reuses H)
  ln_kernel<<<MTOT, 256, 0, stream>>>(out, ln2w, ln2b, H);

  if (bigT){
    // FFN1: single N=4096 GEMM -> T[16384][4096], then one K=4096 FFN2
    gemm256<2><<<(MTOT/256)*(4096/256), 512, 0, stream>>>(
        H, DIMD, W1, DIMD, f1b, nullptr, T, nullptr, 4*DIMD, 4096/256, DIMD);
    gemm256<3><<<(MTOT/256)*(DIMD/256), 512, 0, stream>>>(
        T, 4*DIMD, W2, 4*DIMD, f2b, nullptr, out, nullptr, DIMD, DIMD/256, 4*DIMD);
  } else {
    // FFN in 2 hidden-dim chunks of 2048 (T aliases G/V, out accumulates)
    for (int c = 0; c < 2; ++c){
      const unsigned short* W1c = W1 + (size_t)c * 2048 * DIMD;   // rows [c*2048, ..)
      const unsigned short* W2c = W2 + (size_t)c * 2048;          // k-columns [c*2048, ..)
      gemm256<2><<<(MTOT/256)*(2048/256), 512, 0, stream>>>(
          H, DIMD, W1c, DIMD, f1b + c*2048, nullptr, T, nullptr, 2048, 2048/256, DIMD);
      if (c == 0)
        gemm256<3><<<(MTOT/256)*(DIMD/256), 512, 0, stream>>>(
            T, 2048, W2c, 4*DIMD, f2b, nullptr, out, nullptr, DIMD, DIMD/256, 2048);
      else
        gemm256<4><<<(MTOT/256)*(DIMD/256), 512, 0, stream>>>(
            T, 2048, W2c, 4*DIMD, nullptr, nullptr, out, nullptr, DIMD, DIMD/256, 2048);
    }
  }
}